// Round 3
// baseline (609.416 us; speedup 1.0000x reference)
//
#include <hip/hip_runtime.h>
#include <hip/hip_bf16.h>

#define N_NODES 100000
#define N_EDGES 1600000
#define SLOPE_ 0.2f

typedef __attribute__((ext_vector_type(8))) short bf16x8;
typedef __attribute__((ext_vector_type(4))) float f32x4;

__device__ __forceinline__ short f2bf(float f) {
    __hip_bfloat16 h = __float2bfloat16(f);
    return *reinterpret_cast<short*>(&h);
}
__device__ __forceinline__ float bflo(unsigned u) { return __uint_as_float(u << 16); }
__device__ __forceinline__ float bfhi(unsigned u) { return __uint_as_float(u & 0xFFFF0000u); }
__device__ __forceinline__ float bf2f(short s) {
    return __uint_as_float(((unsigned)(unsigned short)s) << 16);
}

// ---------------- CSR build (col-sorted for gather locality) ----------------
// cnt2[0..N): row counts; cnt2[N..2N): col counts. One combined scan.

__global__ void hist2_k(const int* __restrict__ row, const int* __restrict__ col,
                        int* __restrict__ cnt2) {
    int e = blockIdx.x * 256 + threadIdx.x;  // grid sized exactly E/256
    atomicAdd(&cnt2[row[e]], 1);
    atomicAdd(&cnt2[N_NODES + col[e]], 1);
}

// per-block inclusive scan over 512 elements (256 threads x 2)
__global__ void scanA_k(const int* __restrict__ cnt, int n,
                        int* __restrict__ incl, int* __restrict__ bsum) {
    __shared__ int s[256];
    int t = threadIdx.x;
    int base = blockIdx.x * 512;
    int i0 = base + 2 * t, i1 = i0 + 1;
    int a = (i0 < n) ? cnt[i0] : 0;
    int b = (i1 < n) ? cnt[i1] : 0;
    int p = a + b;
    s[t] = p;
    __syncthreads();
    for (int off = 1; off < 256; off <<= 1) {
        int v = (t >= off) ? s[t - off] : 0;
        __syncthreads();
        s[t] += v;
        __syncthreads();
    }
    int excl = s[t] - p;
    if (i0 < n) incl[i0] = excl + a;
    if (i1 < n) incl[i1] = excl + a + b;
    if (t == 255) bsum[blockIdx.x] = s[255];
}

// exclusive scan of up to 512 block sums (single block, 2 per thread)
__global__ void scanB_k(const int* __restrict__ bsum, int nb, int* __restrict__ boff) {
    __shared__ int s[256];
    int t = threadIdx.x;
    int i0 = 2 * t, i1 = 2 * t + 1;
    int a = (i0 < nb) ? bsum[i0] : 0;
    int b = (i1 < nb) ? bsum[i1] : 0;
    int p = a + b;
    s[t] = p;
    __syncthreads();
    for (int off = 1; off < 256; off <<= 1) {
        int u = (t >= off) ? s[t - off] : 0;
        __syncthreads();
        s[t] += u;
        __syncthreads();
    }
    int excl = s[t] - p;
    if (i0 < nb) boff[i0] = excl;
    if (i1 < nb) boff[i1] = excl + a;
}

// row_ptr[i+1] = inclusive (rows only); cursor2[i] = global exclusive (rows & cols)
__global__ void scanC_k(const int* __restrict__ incl, const int* __restrict__ boff,
                        const int* __restrict__ cnt2, int n2,
                        int* __restrict__ row_ptr, int* __restrict__ cursor2) {
    int i = blockIdx.x * 256 + threadIdx.x;
    if (i < n2) {
        int g = incl[i] + boff[i >> 9];
        cursor2[i] = g - cnt2[i];
        if (i < N_NODES) {
            row_ptr[i + 1] = g;
            if (i == 0) row_ptr[0] = 0;
        }
    }
}

// pass 1: scatter edges into col-sorted staging (ers = row, ecw = {col, w})
__global__ void scatter1_k(const int* __restrict__ row, const int* __restrict__ col,
                           const float* __restrict__ ew, int* __restrict__ cursor2,
                           int* __restrict__ ers, int2* __restrict__ ecw) {
    int e = blockIdx.x * 256 + threadIdx.x;  // grid sized exactly E/256
    int r = row[e], c = col[e];
    float w = ew[e];
    int p = atomicAdd(&cursor2[N_NODES + c], 1) - N_EDGES;  // col prefix starts at E
    ers[p] = r;
    ecw[p] = make_int2(c, __float_as_int(w));
}

// pass 2: walk col-sorted edges, scatter to row-CSR (cols ~ascending per row)
__global__ void scatter2_k(const int* __restrict__ ers, const int2* __restrict__ ecw,
                           int* __restrict__ cursor2, int2* __restrict__ cw) {
    int i = blockIdx.x * 256 + threadIdx.x;  // grid sized exactly E/256
    int r = ers[i];
    int2 x = ecw[i];
    int p = atomicAdd(&cursor2[r], 1);
    cw[p] = x;
}

// ---------------- weight prep: Wt[n][k] = bf16(W[k][n]) ----------------

__global__ void prep_k(const float* __restrict__ W1, const float* __restrict__ W2,
                       short* __restrict__ Wt1, short* __restrict__ Wt2) {
    int i = blockIdx.x * 256 + threadIdx.x;
    if (i < 128 * 256) {
        int n = i >> 8, k = i & 255;
        Wt1[i] = f2bf(W1[k * 128 + n]);
    }
    int j = i - 128 * 256;
    if (j >= 0 && j < 64 * 128) {
        int n = j >> 7, k = j & 127;
        Wt2[j] = f2bf(W2[k * 64 + n]);
    }
}

// ---------------- MFMA GEMM: out[M][COLS](bf16) = A[M][K] @ W[K][COLS] ----------------

template <int K, int COLS, bool ABF16>
__global__ void gemm_mfma(const void* __restrict__ Ap, const short* __restrict__ Wt,
                          short* __restrict__ out, int M) {
    constexpr int NT = COLS / 16;
    int l = threadIdx.x & 63;
    int wv = threadIdx.x >> 6;
    int row0 = blockIdx.x * 64 + wv * 16;
    int ln = l & 15, g = l >> 4;
    int arow = row0 + ln;
    bool rowok = arow < M;
    f32x4 acc[NT];
#pragma unroll
    for (int t = 0; t < NT; t++) acc[t] = (f32x4){0.f, 0.f, 0.f, 0.f};

    for (int k0 = 0; k0 < K; k0 += 32) {
        int kk = k0 + g * 8;
        bf16x8 af = {};
        if constexpr (ABF16) {
            if (rowok) af = *(const bf16x8*)((const short*)Ap + (size_t)arow * K + kk);
        } else {
            if (rowok) {
                const float* ap = (const float*)Ap + (size_t)arow * K + kk;
                float4 u0 = *(const float4*)ap;
                float4 u1 = *(const float4*)(ap + 4);
                af[0] = f2bf(u0.x); af[1] = f2bf(u0.y);
                af[2] = f2bf(u0.z); af[3] = f2bf(u0.w);
                af[4] = f2bf(u1.x); af[5] = f2bf(u1.y);
                af[6] = f2bf(u1.z); af[7] = f2bf(u1.w);
            }
        }
#pragma unroll
        for (int nt = 0; nt < NT; nt++) {
            bf16x8 bfr = *(const bf16x8*)(Wt + (size_t)(nt * 16 + ln) * K + kk);
            acc[nt] = __builtin_amdgcn_mfma_f32_16x16x32_bf16(af, bfr, acc[nt], 0, 0, 0);
        }
    }
#pragma unroll
    for (int nt = 0; nt < NT; nt++) {
#pragma unroll
        for (int r = 0; r < 4; r++) {
            int orow = row0 + g * 4 + r;
            if (orow < M) out[(size_t)orow * COLS + nt * 16 + ln] = f2bf(acc[nt][r]);
        }
    }
}

// ---------------- pull-SpMM: cooperative metadata load + 4x unrolled gathers ----------------

template <int D, bool DROP>
__global__ void spmm_bf(const int* __restrict__ row_ptr, const int2* __restrict__ cw,
                        const short* __restrict__ h,
                        const float* __restrict__ bias, const float* __restrict__ mask,
                        short* __restrict__ out, int n) {
    int wid = (int)((blockIdx.x * (size_t)blockDim.x + threadIdx.x) >> 6);
    int lane = threadIdx.x & 63;
    if (wid >= n) return;
    int s = row_ptr[wid], e = row_ptr[wid + 1];
    float ax = 0.f, ay = 0.f;
    int base = s;
    while (base < e) {
        int m = e - base;
        if (m > 64) m = 64;
        int2 cwv = (lane < m) ? cw[base + lane] : make_int2(0, 0);
        int j = 0;
        for (; j + 4 <= m; j += 4) {
            int c0 = __shfl(cwv.x, j);     float w0 = __uint_as_float(__shfl(cwv.y, j));
            int c1 = __shfl(cwv.x, j + 1); float w1 = __uint_as_float(__shfl(cwv.y, j + 1));
            int c2 = __shfl(cwv.x, j + 2); float w2 = __uint_as_float(__shfl(cwv.y, j + 2));
            int c3 = __shfl(cwv.x, j + 3); float w3 = __uint_as_float(__shfl(cwv.y, j + 3));
            if (D == 128) {
                unsigned u0 = *(const unsigned*)(h + (size_t)c0 * 128 + 2 * lane);
                unsigned u1 = *(const unsigned*)(h + (size_t)c1 * 128 + 2 * lane);
                unsigned u2 = *(const unsigned*)(h + (size_t)c2 * 128 + 2 * lane);
                unsigned u3 = *(const unsigned*)(h + (size_t)c3 * 128 + 2 * lane);
                ax += w0 * bflo(u0); ay += w0 * bfhi(u0);
                ax += w1 * bflo(u1); ay += w1 * bfhi(u1);
                ax += w2 * bflo(u2); ay += w2 * bfhi(u2);
                ax += w3 * bflo(u3); ay += w3 * bfhi(u3);
            } else {
                float v0 = bf2f(h[(size_t)c0 * 64 + lane]);
                float v1 = bf2f(h[(size_t)c1 * 64 + lane]);
                float v2 = bf2f(h[(size_t)c2 * 64 + lane]);
                float v3 = bf2f(h[(size_t)c3 * 64 + lane]);
                ax += w0 * v0 + w1 * v1 + w2 * v2 + w3 * v3;
            }
        }
        for (; j < m; j++) {
            int c0 = __shfl(cwv.x, j);
            float w0 = __uint_as_float(__shfl(cwv.y, j));
            if (D == 128) {
                unsigned u0 = *(const unsigned*)(h + (size_t)c0 * 128 + 2 * lane);
                ax += w0 * bflo(u0); ay += w0 * bfhi(u0);
            } else {
                ax += w0 * bf2f(h[(size_t)c0 * 64 + lane]);
            }
        }
        base += m;
    }
    if (D == 128) {
        float2 b = *(const float2*)(bias + 2 * lane);
        float ox = ax + b.x, oy = ay + b.y;
        ox = ox > 0.f ? ox : SLOPE_ * ox;
        oy = oy > 0.f ? oy : SLOPE_ * oy;
        if (DROP) {
            float2 m2 = *(const float2*)(mask + (size_t)wid * 128 + 2 * lane);
            ox *= m2.x;
            oy *= m2.y;
        }
        unsigned ov = (unsigned)(unsigned short)f2bf(ox) |
                      ((unsigned)(unsigned short)f2bf(oy) << 16);
        *(unsigned*)(out + (size_t)wid * 128 + 2 * lane) = ov;
    } else {
        float o = ax + bias[lane];
        o = o > 0.f ? o : SLOPE_ * o;
        out[(size_t)wid * 64 + lane] = f2bf(o);
    }
}

// ---------------- fused classifier: out = lrelu(h@W3+b3)@W4 + b4 (h bf16) ----------------

__global__ void clf_k(const short* __restrict__ h, const float* __restrict__ W3,
                      const float* __restrict__ b3, const float* __restrict__ W4,
                      const float* __restrict__ b4, float* __restrict__ out) {
    __shared__ float W3s[64][32];
    __shared__ float W4s[32][16];
    __shared__ float b3s[32], b4s[16];
    __shared__ float hs[32][64];
    __shared__ float t4[32][33];  // pad
    int t = threadIdx.x;
    for (int l = t; l < 64 * 32; l += 256) W3s[l / 32][l % 32] = W3[l];
    for (int l = t; l < 32 * 16; l += 256) W4s[l / 16][l % 16] = W4[l];
    if (t < 32) b3s[t] = b3[t];
    if (t < 16) b4s[t] = b4[t];
    int row0 = blockIdx.x * 32;
    {
        bf16x8 v = *(const bf16x8*)(h + (size_t)row0 * 64 + t * 8);
        int r = t >> 3, c0 = (t & 7) << 3;
#pragma unroll
        for (int j = 0; j < 8; j++) hs[r][c0 + j] = bf2f(v[j]);
    }
    __syncthreads();
    for (int l = t; l < 1024; l += 256) {
        int r = l / 32, c = l % 32;
        float a = b3s[c];
#pragma unroll 8
        for (int k = 0; k < 64; k++) a += hs[r][k] * W3s[k][c];
        t4[r][c] = a > 0.f ? a : SLOPE_ * a;
    }
    __syncthreads();
    for (int l = t; l < 512; l += 256) {
        int r = l / 16, c = l % 16;
        float a = b4s[c];
#pragma unroll
        for (int k = 0; k < 32; k++) a += t4[r][k] * W4s[k][c];
        out[(size_t)(row0 + r) * 16 + c] = a;
    }
}

// ---------------- launch ----------------

extern "C" void kernel_launch(void* const* d_in, const int* in_sizes, int n_in,
                              void* d_out, int out_size, void* d_ws, size_t ws_size,
                              hipStream_t stream) {
    const float* x = (const float*)d_in[0];
    const int* row = (const int*)d_in[1];
    const int* col = (const int*)d_in[2];
    const float* ew = (const float*)d_in[3];
    const float* W1 = (const float*)d_in[4];
    const float* b1 = (const float*)d_in[5];
    const float* W2 = (const float*)d_in[6];
    const float* b2 = (const float*)d_in[7];
    const float* W3 = (const float*)d_in[8];
    const float* b3 = (const float*)d_in[9];
    const float* W4 = (const float*)d_in[10];
    const float* b4 = (const float*)d_in[11];
    const float* mask = (const float*)d_in[12];
    float* out = (float*)d_out;

    const int N = N_NODES, E = N_EDGES;
    const int N2 = 2 * N;

    short* h0 = (short*)d_ws;            // N*128 bf16 (gemm1 out)
    short* h1 = h0 + (size_t)N * 128;    // N*128 bf16 (spmm1 out)
    short* h2 = h1 + (size_t)N * 128;    // N*64  bf16 (gemm2 out)
    short* h3 = h2 + (size_t)N * 64;     // N*64  bf16 (spmm2 out)
    short* Wt1 = h3 + (size_t)N * 64;    // 128*256 bf16
    short* Wt2 = Wt1 + 128 * 256;        // 64*128 bf16
    int* cnt2 = (int*)(Wt2 + 64 * 128);  // 2N
    int* incl = cnt2 + N2;               // 2N
    int* row_ptr = incl + N2;            // N+1
    int* cursor2 = row_ptr + N + 1;      // 2N
    int* bsum = cursor2 + N2;            // 512
    int* boff = bsum + 512;              // 512
    int2* cw = (int2*)(boff + 512);      // E int2
    // staging aliases h0 (dead until gemm1 runs, after scatter2)
    int* ers = (int*)h0;                 // E
    int2* ecw = (int2*)(ers + E);        // E int2 (6.4+12.8 <= 25.6MB)

    int nbScan = (N2 + 511) / 512;  // 391 <= 512

    hipMemsetAsync(cnt2, 0, (size_t)N2 * sizeof(int), stream);
    hist2_k<<<E / 256, 256, 0, stream>>>(row, col, cnt2);
    scanA_k<<<nbScan, 256, 0, stream>>>(cnt2, N2, incl, bsum);
    scanB_k<<<1, 256, 0, stream>>>(bsum, nbScan, boff);
    scanC_k<<<(N2 + 255) / 256, 256, 0, stream>>>(incl, boff, cnt2, N2, row_ptr, cursor2);
    scatter1_k<<<E / 256, 256, 0, stream>>>(row, col, ew, cursor2, ers, ecw);
    scatter2_k<<<E / 256, 256, 0, stream>>>(ers, ecw, cursor2, cw);
    prep_k<<<160, 256, 0, stream>>>(W1, W2, Wt1, Wt2);

    gemm_mfma<256, 128, false><<<(N + 63) / 64, 256, 0, stream>>>(x, Wt1, h0, N);
    spmm_bf<128, true><<<(N + 3) / 4, 256, 0, stream>>>(row_ptr, cw, h0, b1, mask, h1, N);
    gemm_mfma<128, 64, true><<<(N + 63) / 64, 256, 0, stream>>>(h1, Wt2, h2, N);
    spmm_bf<64, false><<<(N + 3) / 4, 256, 0, stream>>>(row_ptr, cw, h2, b2, nullptr, h3, N);
    clf_k<<<N / 32, 256, 0, stream>>>(h3, W3, b3, W4, b4, out);
}